// Round 1
// baseline (580.960 us; speedup 1.0000x reference)
//
#include <hip/hip_runtime.h>
#include <hip/hip_bf16.h>
#include <cstdint>
#include <cstddef>

// Problem constants
#define T_DIM 2048
#define B_DIM 2
#define E_DIM 1024
#define H_DIM 16
#define HD_DIM 64
#define M_ROWS 4096   // T*B
#define BH_DIM 32     // B*H

typedef __attribute__((ext_vector_type(8))) short bf16x8;
typedef __attribute__((ext_vector_type(4))) float f32x4;

__device__ __forceinline__ short f2bf(float x) {
  unsigned u = __float_as_uint(x);
  u += 0x7fffu + ((u >> 16) & 1u);
  return (short)(u >> 16);
}

__device__ __forceinline__ f32x4 mfma_bf16(bf16x8 a, bf16x8 b, f32x4 c) {
  return __builtin_amdgcn_mfma_f32_16x16x32_bf16(a, b, c, 0, 0, 0);
}

__device__ __forceinline__ void gload_lds16(const void* g, void* l) {
  __builtin_amdgcn_global_load_lds(
      (const __attribute__((address_space(1))) void*)g,
      (__attribute__((address_space(3))) void*)l,
      16, 0, 0);
}

// ---------------------------------------------------------------------------
// f32 -> bf16 conversion (vectorized), n4 = n/4
// ---------------------------------------------------------------------------
__global__ __launch_bounds__(256) void cvt_bf16_kernel(const float* __restrict__ src,
                                                       short* __restrict__ dst, int n4) {
  int i = blockIdx.x * blockDim.x + threadIdx.x;
  if (i < n4) {
    float4 v = ((const float4*)src)[i];
    short4 o;
    o.x = f2bf(v.x); o.y = f2bf(v.y); o.z = f2bf(v.z); o.w = f2bf(v.w);
    ((short4*)dst)[i] = o;
  }
}

// ---------------------------------------------------------------------------
// Projection GEMM: C[row,col] = sum_k A[row,k] * W[col,k] + bias[col]
// A: M_ROWS x 1024 bf16 (row-major), W: 1024 x 1024 bf16 (row-major = B^T layout)
// 128x128 tile, BK=32, 256 threads (4 waves 2x2), global_load_lds staging.
// mode 0: q (scaled 1/8, to q_s[bh][t][hd])
// mode 1: k (to k_s[bh][t][hd])
// mode 2: v (to vT[bh][hd][t])
// mode 3: out (f32 to outf[row*1024+col])
// mode_in < 0 -> mode = blockIdx.z (batched qkv)
// ---------------------------------------------------------------------------
__global__ __launch_bounds__(256) void proj_gemm_kernel(
    const short* __restrict__ A0, const short* __restrict__ W0,
    const float* __restrict__ b0,
    short* __restrict__ q_s, short* __restrict__ k_s, short* __restrict__ vT,
    float* __restrict__ outf, int mode_in) {
  int mode = (mode_in < 0) ? (int)blockIdx.z : mode_in;
  const short* A = (mode_in < 0) ? A0 + (size_t)mode * (size_t)M_ROWS * 1024 : A0;
  const short* W = W0 + (size_t)mode * 1024 * 1024;
  const float* bias = (mode_in < 0) ? b0 + mode * 1024 : b0;

  __shared__ short As[128 * 32];
  __shared__ short Bs[128 * 32];

  int tid = threadIdx.x;
  int lane = tid & 63;
  int wave = tid >> 6;
  int wm = wave >> 1, wn = wave & 1;
  int brow = blockIdx.y * 128;
  int bcol = blockIdx.x * 128;

  f32x4 acc[4][4];
#pragma unroll
  for (int i = 0; i < 4; i++)
#pragma unroll
    for (int j = 0; j < 4; j++) acc[i][j] = (f32x4){0.f, 0.f, 0.f, 0.f};

  for (int k0 = 0; k0 < 1024; k0 += 32) {
#pragma unroll
    for (int j = 0; j < 2; j++) {
      int chunk = wave * 2 + j;            // 0..7, 16 rows each
      int row = chunk * 16 + (lane >> 2);  // tile row this lane fetches
      int col = (lane & 3) * 8;            // bf16 col offset within 32-wide K slab
      gload_lds16(A + (size_t)(brow + row) * 1024 + k0 + col, &As[chunk * 512]);
      gload_lds16(W + (size_t)(bcol + row) * 1024 + k0 + col, &Bs[chunk * 512]);
    }
    __syncthreads();

    bf16x8 af[4], bf_[4];
#pragma unroll
    for (int mi = 0; mi < 4; mi++)
      af[mi] = *(const bf16x8*)&As[(wm * 64 + mi * 16 + (lane & 15)) * 32 + (lane >> 4) * 8];
#pragma unroll
    for (int ni = 0; ni < 4; ni++)
      bf_[ni] = *(const bf16x8*)&Bs[(wn * 64 + ni * 16 + (lane & 15)) * 32 + (lane >> 4) * 8];
#pragma unroll
    for (int mi = 0; mi < 4; mi++)
#pragma unroll
      for (int ni = 0; ni < 4; ni++)
        acc[mi][ni] = mfma_bf16(af[mi], bf_[ni], acc[mi][ni]);
    __syncthreads();
  }

  // Epilogue. C layout: col = lane&15, row = (lane>>4)*4 + reg.
#pragma unroll
  for (int mi = 0; mi < 4; mi++) {
#pragma unroll
    for (int ni = 0; ni < 4; ni++) {
      int col = bcol + wn * 64 + ni * 16 + (lane & 15);
      float bv = bias[col];
      int row0 = brow + wm * 64 + mi * 16 + (lane >> 4) * 4;
#pragma unroll
      for (int r = 0; r < 4; r++) {
        int row = row0 + r;
        float val = acc[mi][ni][r] + bv;
        int t = row >> 1, b = row & 1;
        int h = col >> 6, hd = col & 63;
        if (mode == 0) {
          q_s[((size_t)((b << 4) + h) * T_DIM + t) * HD_DIM + hd] = f2bf(val * 0.125f);
        } else if (mode == 1) {
          k_s[((size_t)((b << 4) + h) * T_DIM + t) * HD_DIM + hd] = f2bf(val);
        } else if (mode == 2) {
          vT[((size_t)((b << 4) + h) * HD_DIM + hd) * T_DIM + t] = f2bf(val);
        } else {
          outf[(size_t)row * 1024 + col] = val;
        }
      }
    }
  }
}

// ---------------------------------------------------------------------------
// Flash attention forward: per (bh, 64-row t-block); each wave owns 16 t rows.
// Online softmax; accumulates PV; writes AO (bf16, [t*2+b][e]) and m, 1/l stats.
// q_s is pre-scaled by 1/8.
// ---------------------------------------------------------------------------
__global__ __launch_bounds__(256) void flash_fwd_kernel(
    const short* __restrict__ q_s, const short* __restrict__ k_s,
    const short* __restrict__ vT, short* __restrict__ AO,
    float* __restrict__ m_ws, float* __restrict__ li_ws) {
  int bh = blockIdx.y;
  int lane = threadIdx.x & 63;
  int wave = threadIdx.x >> 6;
  int t0 = blockIdx.x * 64 + wave * 16;

  const short* qb = q_s + (size_t)bh * T_DIM * HD_DIM;
  const short* kb = k_s + (size_t)bh * T_DIM * HD_DIM;
  const short* vb = vT + (size_t)bh * HD_DIM * T_DIM;

  bf16x8 qf0 = *(const bf16x8*)&qb[(t0 + (lane & 15)) * HD_DIM + (lane >> 4) * 8];
  bf16x8 qf1 = *(const bf16x8*)&qb[(t0 + (lane & 15)) * HD_DIM + 32 + (lane >> 4) * 8];

  f32x4 acc[4];
#pragma unroll
  for (int i = 0; i < 4; i++) acc[i] = (f32x4){0.f, 0.f, 0.f, 0.f};
  float m[4], l[4];
#pragma unroll
  for (int r = 0; r < 4; r++) { m[r] = -INFINITY; l[r] = 0.f; }

  __shared__ short p_lds[4][512];  // per-wave 16x32 P tile
  short* pl = p_lds[wave];

  for (int s0 = 0; s0 < T_DIM; s0 += 32) {
    f32x4 S[2];
#pragma unroll
    for (int sn = 0; sn < 2; sn++) {
      const short* kr = &kb[(s0 + sn * 16 + (lane & 15)) * HD_DIM + (lane >> 4) * 8];
      bf16x8 kf0 = *(const bf16x8*)kr;
      bf16x8 kf1 = *(const bf16x8*)(kr + 32);
      f32x4 z = (f32x4){0.f, 0.f, 0.f, 0.f};
      z = mfma_bf16(qf0, kf0, z);
      z = mfma_bf16(qf1, kf1, z);
      S[sn] = z;
    }
    float sc[4];
#pragma unroll
    for (int r = 0; r < 4; r++) {
      float tmax = fmaxf(S[0][r], S[1][r]);
      tmax = fmaxf(tmax, __shfl_xor(tmax, 1));
      tmax = fmaxf(tmax, __shfl_xor(tmax, 2));
      tmax = fmaxf(tmax, __shfl_xor(tmax, 4));
      tmax = fmaxf(tmax, __shfl_xor(tmax, 8));
      float mn = fmaxf(m[r], tmax);
      float p0 = __expf(S[0][r] - mn);
      float p1 = __expf(S[1][r] - mn);
      S[0][r] = p0; S[1][r] = p1;
      float ps = p0 + p1;
      ps += __shfl_xor(ps, 1);
      ps += __shfl_xor(ps, 2);
      ps += __shfl_xor(ps, 4);
      ps += __shfl_xor(ps, 8);
      sc[r] = __expf(m[r] - mn);
      l[r] = l[r] * sc[r] + ps;
      m[r] = mn;
    }
#pragma unroll
    for (int hdt = 0; hdt < 4; hdt++)
#pragma unroll
      for (int r = 0; r < 4; r++) acc[hdt][r] *= sc[r];

    // P tile (16x32) -> LDS for A-fragment relayout
#pragma unroll
    for (int sn = 0; sn < 2; sn++)
#pragma unroll
      for (int r = 0; r < 4; r++)
        pl[((lane >> 4) * 4 + r) * 32 + sn * 16 + (lane & 15)] = f2bf(S[sn][r]);
    __syncthreads();
    bf16x8 pf = *(const bf16x8*)&pl[(lane & 15) * 32 + (lane >> 4) * 8];
#pragma unroll
    for (int hdt = 0; hdt < 4; hdt++) {
      bf16x8 vf = *(const bf16x8*)&vb[(hdt * 16 + (lane & 15)) * T_DIM + s0 + (lane >> 4) * 8];
      acc[hdt] = mfma_bf16(pf, vf, acc[hdt]);
    }
    __syncthreads();
  }

  float li[4];
#pragma unroll
  for (int r = 0; r < 4; r++) li[r] = 1.0f / l[r];
  int b = bh >> 4, h = bh & 15;
#pragma unroll
  for (int hdt = 0; hdt < 4; hdt++) {
#pragma unroll
    for (int r = 0; r < 4; r++) {
      int t = t0 + (lane >> 4) * 4 + r;
      AO[(size_t)(t * 2 + b) * E_DIM + h * 64 + hdt * 16 + (lane & 15)] =
          f2bf(acc[hdt][r] * li[r]);
    }
  }
  if ((lane & 15) == 0) {
#pragma unroll
    for (int r = 0; r < 4; r++) {
      int t = t0 + (lane >> 4) * 4 + r;
      m_ws[bh * T_DIM + t] = m[r];
      li_ws[bh * T_DIM + t] = li[r];
    }
  }
}

// ---------------------------------------------------------------------------
// attn_weights: out[b,t,s] = (1/H) * sum_h exp(score[bh,t,s] - m[bh,t]) * linv[bh,t]
// block = (ss, tt, b); 4 waves cover 32x32 (t,s) tile as 2x2 subtiles of 16x16.
// ---------------------------------------------------------------------------
__global__ __launch_bounds__(256) void attn_weights_kernel(
    const short* __restrict__ q_s, const short* __restrict__ k_s,
    const float* __restrict__ m_ws, const float* __restrict__ li_ws,
    float* __restrict__ wout) {
  int b = blockIdx.z;
  int lane = threadIdx.x & 63;
  int wave = threadIdx.x >> 6;
  int tbase = blockIdx.y * 32 + (wave >> 1) * 16;
  int sbase = blockIdx.x * 32 + (wave & 1) * 16;

  float wsum[4] = {0.f, 0.f, 0.f, 0.f};
#pragma unroll 1
  for (int h = 0; h < 16; h++) {
    int bh = b * 16 + h;
    const short* qb = q_s + (size_t)bh * T_DIM * HD_DIM;
    const short* kb = k_s + (size_t)bh * T_DIM * HD_DIM;
    bf16x8 qf0 = *(const bf16x8*)&qb[(tbase + (lane & 15)) * HD_DIM + (lane >> 4) * 8];
    bf16x8 qf1 = *(const bf16x8*)&qb[(tbase + (lane & 15)) * HD_DIM + 32 + (lane >> 4) * 8];
    bf16x8 kf0 = *(const bf16x8*)&kb[(sbase + (lane & 15)) * HD_DIM + (lane >> 4) * 8];
    bf16x8 kf1 = *(const bf16x8*)&kb[(sbase + (lane & 15)) * HD_DIM + 32 + (lane >> 4) * 8];
    f32x4 z = (f32x4){0.f, 0.f, 0.f, 0.f};
    z = mfma_bf16(qf0, kf0, z);
    z = mfma_bf16(qf1, kf1, z);
#pragma unroll
    for (int r = 0; r < 4; r++) {
      int t = tbase + (lane >> 4) * 4 + r;
      wsum[r] += __expf(z[r] - m_ws[bh * T_DIM + t]) * li_ws[bh * T_DIM + t];
    }
  }
#pragma unroll
  for (int r = 0; r < 4; r++) {
    int t = tbase + (lane >> 4) * 4 + r;
    wout[((size_t)b * T_DIM + t) * T_DIM + sbase + (lane & 15)] = wsum[r] * (1.0f / 16.0f);
  }
}

// ---------------------------------------------------------------------------
// Launch
// ---------------------------------------------------------------------------
extern "C" void kernel_launch(void* const* d_in, const int* in_sizes, int n_in,
                              void* d_out, int out_size, void* d_ws, size_t ws_size,
                              hipStream_t stream) {
  const float* query = (const float*)d_in[0];
  const float* key = (const float*)d_in[1];
  const float* value = (const float*)d_in[2];
  const float* in_proj_w = (const float*)d_in[3];
  const float* in_proj_b = (const float*)d_in[4];
  const float* out_w = (const float*)d_in[5];
  const float* out_b = (const float*)d_in[6];
  // gate params d_in[7..12] are dead: top_k == out_features -> mask == all-ones.

  float* out = (float*)d_out;                 // attn_output: 4096*1024 f32
  float* wout = out + (size_t)M_ROWS * E_DIM; // attn_weights: 2*2048*2048 f32

  char* ws = (char*)d_ws;
  short* Wb = (short*)ws;                               // 4M bf16 (qkv + out weights)
  short* Xb = (short*)(ws + (8ull << 20));              // 12M bf16 (q,k,v inputs)
  short* q_s = (short*)(ws + (32ull << 20));            // 4M bf16
  short* k_s = (short*)(ws + (40ull << 20));            // 4M bf16
  short* vT = (short*)(ws + (48ull << 20));             // 4M bf16
  short* AO = (short*)(ws + (56ull << 20));             // 4M bf16
  float* m_ws = (float*)(ws + (64ull << 20));           // 64K f32
  float* li_ws = (float*)(ws + (64ull << 20) + (256ull << 10));

  // 1. convert inputs + weights to bf16
  cvt_bf16_kernel<<<4096, 256, 0, stream>>>(query, Xb, 1048576);
  cvt_bf16_kernel<<<4096, 256, 0, stream>>>(key, Xb + 4194304, 1048576);
  cvt_bf16_kernel<<<4096, 256, 0, stream>>>(value, Xb + 8388608, 1048576);
  cvt_bf16_kernel<<<3072, 256, 0, stream>>>(in_proj_w, Wb, 786432);
  cvt_bf16_kernel<<<1024, 256, 0, stream>>>(out_w, Wb + 3145728, 262144);

  // 2. q/k/v projections (batched over z)
  proj_gemm_kernel<<<dim3(8, 32, 3), 256, 0, stream>>>(
      Xb, Wb, in_proj_b, q_s, k_s, vT, nullptr, -1);

  // 3. flash attention (PV + stats)
  flash_fwd_kernel<<<dim3(32, 32), 256, 0, stream>>>(q_s, k_s, vT, AO, m_ws, li_ws);

  // 4. attn_weights (head-averaged softmax)
  attn_weights_kernel<<<dim3(64, 64, 2), 256, 0, stream>>>(q_s, k_s, m_ws, li_ws, wout);

  // 5. output projection -> d_out
  proj_gemm_kernel<<<dim3(8, 32, 1), 256, 0, stream>>>(
      AO, Wb, out_b, nullptr, nullptr, nullptr, out, 3);
}

// Round 2
// 474.067 us; speedup vs baseline: 1.2255x; 1.2255x over previous
//
#include <hip/hip_runtime.h>
#include <hip/hip_bf16.h>
#include <cstdint>
#include <cstddef>

// Problem constants
#define T_DIM 2048
#define B_DIM 2
#define E_DIM 1024
#define H_DIM 16
#define HD_DIM 64
#define M_ROWS 4096   // T*B
#define BH_DIM 32     // B*H

typedef __attribute__((ext_vector_type(8))) short bf16x8;
typedef __attribute__((ext_vector_type(4))) float f32x4;

__device__ __forceinline__ short f2bf(float x) {
  unsigned u = __float_as_uint(x);
  u += 0x7fffu + ((u >> 16) & 1u);
  return (short)(u >> 16);
}

__device__ __forceinline__ f32x4 mfma_bf16(bf16x8 a, bf16x8 b, f32x4 c) {
  return __builtin_amdgcn_mfma_f32_16x16x32_bf16(a, b, c, 0, 0, 0);
}

__device__ __forceinline__ void gload_lds16(const void* g, void* l) {
  __builtin_amdgcn_global_load_lds(
      (const __attribute__((address_space(1))) void*)g,
      (__attribute__((address_space(3))) void*)l,
      16, 0, 0);
}

// ---------------------------------------------------------------------------
// f32 -> bf16 conversion (vectorized), n4 = n/4
// ---------------------------------------------------------------------------
__global__ __launch_bounds__(256) void cvt_bf16_kernel(const float* __restrict__ src,
                                                       short* __restrict__ dst, int n4) {
  int i = blockIdx.x * blockDim.x + threadIdx.x;
  if (i < n4) {
    float4 v = ((const float4*)src)[i];
    short4 o;
    o.x = f2bf(v.x); o.y = f2bf(v.y); o.z = f2bf(v.z); o.w = f2bf(v.w);
    ((short4*)dst)[i] = o;
  }
}

// ---------------------------------------------------------------------------
// Projection GEMM: C[row,col] = sum_k A[row,k] * W[col,k] + bias[col]
// 128x128 tile, BK=32, 256 threads (4 waves 2x2), global_load_lds staging.
// mode 0: q (scaled 1/8) / 1: k / 2: v (transposed) / 3: out (f32)
// ---------------------------------------------------------------------------
__global__ __launch_bounds__(256) void proj_gemm_kernel(
    const short* __restrict__ A0, const short* __restrict__ W0,
    const float* __restrict__ b0,
    short* __restrict__ q_s, short* __restrict__ k_s, short* __restrict__ vT,
    float* __restrict__ outf, int mode_in) {
  int mode = (mode_in < 0) ? (int)blockIdx.z : mode_in;
  const short* A = (mode_in < 0) ? A0 + (size_t)mode * (size_t)M_ROWS * 1024 : A0;
  const short* W = W0 + (size_t)mode * 1024 * 1024;
  const float* bias = (mode_in < 0) ? b0 + mode * 1024 : b0;

  __shared__ short As[128 * 32];
  __shared__ short Bs[128 * 32];

  int tid = threadIdx.x;
  int lane = tid & 63;
  int wave = tid >> 6;
  int wm = wave >> 1, wn = wave & 1;
  int brow = blockIdx.y * 128;
  int bcol = blockIdx.x * 128;

  f32x4 acc[4][4];
#pragma unroll
  for (int i = 0; i < 4; i++)
#pragma unroll
    for (int j = 0; j < 4; j++) acc[i][j] = (f32x4){0.f, 0.f, 0.f, 0.f};

  for (int k0 = 0; k0 < 1024; k0 += 32) {
#pragma unroll
    for (int j = 0; j < 2; j++) {
      int chunk = wave * 2 + j;            // 0..7, 16 rows each
      int row = chunk * 16 + (lane >> 2);
      int col = (lane & 3) * 8;
      gload_lds16(A + (size_t)(brow + row) * 1024 + k0 + col, &As[chunk * 512]);
      gload_lds16(W + (size_t)(bcol + row) * 1024 + k0 + col, &Bs[chunk * 512]);
    }
    __syncthreads();

    bf16x8 af[4], bf_[4];
#pragma unroll
    for (int mi = 0; mi < 4; mi++)
      af[mi] = *(const bf16x8*)&As[(wm * 64 + mi * 16 + (lane & 15)) * 32 + (lane >> 4) * 8];
#pragma unroll
    for (int ni = 0; ni < 4; ni++)
      bf_[ni] = *(const bf16x8*)&Bs[(wn * 64 + ni * 16 + (lane & 15)) * 32 + (lane >> 4) * 8];
#pragma unroll
    for (int mi = 0; mi < 4; mi++)
#pragma unroll
      for (int ni = 0; ni < 4; ni++)
        acc[mi][ni] = mfma_bf16(af[mi], bf_[ni], acc[mi][ni]);
    __syncthreads();
  }

#pragma unroll
  for (int mi = 0; mi < 4; mi++) {
#pragma unroll
    for (int ni = 0; ni < 4; ni++) {
      int col = bcol + wn * 64 + ni * 16 + (lane & 15);
      float bv = bias[col];
      int row0 = brow + wm * 64 + mi * 16 + (lane >> 4) * 4;
#pragma unroll
      for (int r = 0; r < 4; r++) {
        int row = row0 + r;
        float val = acc[mi][ni][r] + bv;
        int t = row >> 1, b = row & 1;
        int h = col >> 6, hd = col & 63;
        if (mode == 0) {
          q_s[((size_t)((b << 4) + h) * T_DIM + t) * HD_DIM + hd] = f2bf(val * 0.125f);
        } else if (mode == 1) {
          k_s[((size_t)((b << 4) + h) * T_DIM + t) * HD_DIM + hd] = f2bf(val);
        } else if (mode == 2) {
          vT[((size_t)((b << 4) + h) * HD_DIM + hd) * T_DIM + t] = f2bf(val);
        } else {
          outf[(size_t)row * 1024 + col] = val;
        }
      }
    }
  }
}

// ---------------------------------------------------------------------------
// Flash attention forward. Writes AO (bf16) and c[bh][t] = -(m + log l).
// q_s is pre-scaled by 1/8.
// ---------------------------------------------------------------------------
__global__ __launch_bounds__(256) void flash_fwd_kernel(
    const short* __restrict__ q_s, const short* __restrict__ k_s,
    const short* __restrict__ vT, short* __restrict__ AO,
    float* __restrict__ c_ws) {
  int bh = blockIdx.y;
  int lane = threadIdx.x & 63;
  int wave = threadIdx.x >> 6;
  int t0 = blockIdx.x * 64 + wave * 16;

  const short* qb = q_s + (size_t)bh * T_DIM * HD_DIM;
  const short* kb = k_s + (size_t)bh * T_DIM * HD_DIM;
  const short* vb = vT + (size_t)bh * HD_DIM * T_DIM;

  bf16x8 qf0 = *(const bf16x8*)&qb[(t0 + (lane & 15)) * HD_DIM + (lane >> 4) * 8];
  bf16x8 qf1 = *(const bf16x8*)&qb[(t0 + (lane & 15)) * HD_DIM + 32 + (lane >> 4) * 8];

  f32x4 acc[4];
#pragma unroll
  for (int i = 0; i < 4; i++) acc[i] = (f32x4){0.f, 0.f, 0.f, 0.f};
  float m[4], l[4];
#pragma unroll
  for (int r = 0; r < 4; r++) { m[r] = -INFINITY; l[r] = 0.f; }

  __shared__ short p_lds[4][512];  // per-wave 16x32 P tile
  short* pl = p_lds[wave];

  for (int s0 = 0; s0 < T_DIM; s0 += 32) {
    f32x4 S[2];
#pragma unroll
    for (int sn = 0; sn < 2; sn++) {
      const short* kr = &kb[(s0 + sn * 16 + (lane & 15)) * HD_DIM + (lane >> 4) * 8];
      bf16x8 kf0 = *(const bf16x8*)kr;
      bf16x8 kf1 = *(const bf16x8*)(kr + 32);
      f32x4 z = (f32x4){0.f, 0.f, 0.f, 0.f};
      z = mfma_bf16(qf0, kf0, z);
      z = mfma_bf16(qf1, kf1, z);
      S[sn] = z;
    }
    float sc[4];
#pragma unroll
    for (int r = 0; r < 4; r++) {
      float tmax = fmaxf(S[0][r], S[1][r]);
      tmax = fmaxf(tmax, __shfl_xor(tmax, 1));
      tmax = fmaxf(tmax, __shfl_xor(tmax, 2));
      tmax = fmaxf(tmax, __shfl_xor(tmax, 4));
      tmax = fmaxf(tmax, __shfl_xor(tmax, 8));
      float mn = fmaxf(m[r], tmax);
      float p0 = __expf(S[0][r] - mn);
      float p1 = __expf(S[1][r] - mn);
      S[0][r] = p0; S[1][r] = p1;
      float ps = p0 + p1;
      ps += __shfl_xor(ps, 1);
      ps += __shfl_xor(ps, 2);
      ps += __shfl_xor(ps, 4);
      ps += __shfl_xor(ps, 8);
      sc[r] = __expf(m[r] - mn);
      l[r] = l[r] * sc[r] + ps;
      m[r] = mn;
    }
#pragma unroll
    for (int hdt = 0; hdt < 4; hdt++)
#pragma unroll
      for (int r = 0; r < 4; r++) acc[hdt][r] *= sc[r];

#pragma unroll
    for (int sn = 0; sn < 2; sn++)
#pragma unroll
      for (int r = 0; r < 4; r++)
        pl[((lane >> 4) * 4 + r) * 32 + sn * 16 + (lane & 15)] = f2bf(S[sn][r]);
    __syncthreads();
    bf16x8 pf = *(const bf16x8*)&pl[(lane & 15) * 32 + (lane >> 4) * 8];
#pragma unroll
    for (int hdt = 0; hdt < 4; hdt++) {
      bf16x8 vf = *(const bf16x8*)&vb[(hdt * 16 + (lane & 15)) * T_DIM + s0 + (lane >> 4) * 8];
      acc[hdt] = mfma_bf16(pf, vf, acc[hdt]);
    }
    __syncthreads();
  }

  float li[4];
#pragma unroll
  for (int r = 0; r < 4; r++) li[r] = 1.0f / l[r];
  int b = bh >> 4, h = bh & 15;
#pragma unroll
  for (int hdt = 0; hdt < 4; hdt++) {
#pragma unroll
    for (int r = 0; r < 4; r++) {
      int t = t0 + (lane >> 4) * 4 + r;
      AO[(size_t)(t * 2 + b) * E_DIM + h * 64 + hdt * 16 + (lane & 15)] =
          f2bf(acc[hdt][r] * li[r]);
    }
  }
  if ((lane & 15) == 0) {
#pragma unroll
    for (int r = 0; r < 4; r++) {
      int t = t0 + (lane >> 4) * 4 + r;
      c_ws[bh * T_DIM + t] = -(m[r] + __logf(l[r]));
    }
  }
}

// ---------------------------------------------------------------------------
// attn_weights: out[b,t,s] = (1/H) * sum_h exp(score[bh,t,s] + c[bh,t])
// Block: 64 t-rows (4 waves x 16) x 64 s-cols, 16 heads in 4 groups of 4.
// q fragments + c in registers across the s sweep; k loaded with 4-head ILP.
// ---------------------------------------------------------------------------
__global__ __launch_bounds__(256) void attn_weights_kernel(
    const short* __restrict__ q_s, const short* __restrict__ k_s,
    const float* __restrict__ c_ws, float* __restrict__ wout) {
  int b = blockIdx.z;
  int lane = threadIdx.x & 63;
  int wave = threadIdx.x >> 6;
  int tw = blockIdx.y * 64 + wave * 16;  // wave's t-row base (16 rows)
  int sbase = blockIdx.x * 64;           // block's s-chunk (64 cols)

  int rr = lane & 15;   // fragment row/col index
  int cg = lane >> 4;   // k-slice group
  int trow = tw + rr;   // A-operand t row for this lane
  int tq = tw + cg * 4; // accumulator row base for this lane

  float wsum[4][4];
#pragma unroll
  for (int st = 0; st < 4; st++)
#pragma unroll
    for (int r = 0; r < 4; r++) wsum[st][r] = 0.f;

#pragma unroll 1
  for (int hg = 0; hg < 4; hg++) {
    bf16x8 qf[4][2];
    float4 cc[4];
#pragma unroll
    for (int h = 0; h < 4; h++) {
      int bh = b * 16 + hg * 4 + h;
      const short* qb = q_s + (size_t)bh * T_DIM * HD_DIM;
      qf[h][0] = *(const bf16x8*)&qb[trow * HD_DIM + cg * 8];
      qf[h][1] = *(const bf16x8*)&qb[trow * HD_DIM + 32 + cg * 8];
      cc[h] = *(const float4*)&c_ws[(size_t)bh * T_DIM + tq];
    }
#pragma unroll
    for (int st = 0; st < 4; st++) {
      int s0 = sbase + st * 16;
#pragma unroll
      for (int h = 0; h < 4; h++) {
        int bh = b * 16 + hg * 4 + h;
        const short* kb = k_s + ((size_t)bh * T_DIM + s0 + rr) * HD_DIM;
        bf16x8 kf0 = *(const bf16x8*)&kb[cg * 8];
        bf16x8 kf1 = *(const bf16x8*)&kb[32 + cg * 8];
        f32x4 z = (f32x4){0.f, 0.f, 0.f, 0.f};
        z = mfma_bf16(qf[h][0], kf0, z);
        z = mfma_bf16(qf[h][1], kf1, z);
        wsum[st][0] += __expf(z[0] + cc[h].x);
        wsum[st][1] += __expf(z[1] + cc[h].y);
        wsum[st][2] += __expf(z[2] + cc[h].z);
        wsum[st][3] += __expf(z[3] + cc[h].w);
      }
    }
  }

#pragma unroll
  for (int st = 0; st < 4; st++)
#pragma unroll
    for (int r = 0; r < 4; r++)
      wout[((size_t)b * T_DIM + tq + r) * T_DIM + sbase + st * 16 + rr] =
          wsum[st][r] * 0.0625f;
}

// ---------------------------------------------------------------------------
// Launch
// ---------------------------------------------------------------------------
extern "C" void kernel_launch(void* const* d_in, const int* in_sizes, int n_in,
                              void* d_out, int out_size, void* d_ws, size_t ws_size,
                              hipStream_t stream) {
  const float* query = (const float*)d_in[0];
  const float* key = (const float*)d_in[1];
  const float* value = (const float*)d_in[2];
  const float* in_proj_w = (const float*)d_in[3];
  const float* in_proj_b = (const float*)d_in[4];
  const float* out_w = (const float*)d_in[5];
  const float* out_b = (const float*)d_in[6];
  // gate params d_in[7..12] are dead: top_k == out_features -> mask == all-ones.

  float* out = (float*)d_out;                 // attn_output: 4096*1024 f32
  float* wout = out + (size_t)M_ROWS * E_DIM; // attn_weights: 2*2048*2048 f32

  char* ws = (char*)d_ws;
  short* Wb = (short*)ws;                               // qkv + out weights bf16
  short* Xb = (short*)(ws + (8ull << 20));              // q,k,v inputs bf16
  short* q_s = (short*)(ws + (32ull << 20));
  short* k_s = (short*)(ws + (40ull << 20));
  short* vT = (short*)(ws + (48ull << 20));
  short* AO = (short*)(ws + (56ull << 20));
  float* c_ws = (float*)(ws + (64ull << 20));           // 256KB f32 stats

  // 1. convert inputs + weights to bf16
  cvt_bf16_kernel<<<4096, 256, 0, stream>>>(query, Xb, 1048576);
  cvt_bf16_kernel<<<4096, 256, 0, stream>>>(key, Xb + 4194304, 1048576);
  cvt_bf16_kernel<<<4096, 256, 0, stream>>>(value, Xb + 8388608, 1048576);
  cvt_bf16_kernel<<<3072, 256, 0, stream>>>(in_proj_w, Wb, 786432);
  cvt_bf16_kernel<<<1024, 256, 0, stream>>>(out_w, Wb + 3145728, 262144);

  // 2. q/k/v projections (batched over z)
  proj_gemm_kernel<<<dim3(8, 32, 3), 256, 0, stream>>>(
      Xb, Wb, in_proj_b, q_s, k_s, vT, nullptr, -1);

  // 3. flash attention (PV + stats)
  flash_fwd_kernel<<<dim3(32, 32), 256, 0, stream>>>(q_s, k_s, vT, AO, c_ws);

  // 4. attn_weights (head-averaged softmax)
  attn_weights_kernel<<<dim3(32, 32, 2), 256, 0, stream>>>(q_s, k_s, c_ws, wout);

  // 5. output projection -> d_out
  proj_gemm_kernel<<<dim3(8, 32, 1), 256, 0, stream>>>(
      AO, Wb, out_b, nullptr, nullptr, nullptr, out, 3);
}